// Round 5
// baseline (220.203 us; speedup 1.0000x reference)
//
#include <hip/hip_runtime.h>
#include <cstdint>
#include <cstddef>

// Problem constants (VectorQuantizer: L=32768, D=64, N_E=16384, beta=0.25)
#define L_TOK 32768
#define D_DIM 64
#define NE    16384
#define GCHUNKS 8              // N split across grid (8 -> 8192 waves total)
#define NPB   (NE / GCHUNKS)   // 2048 n per block
#define BN    128              // n per LDS stage chunk (double-buffered)
#define NCH   (NPB / BN)       // 16 chunks per block
#define WROWS 32               // rows per wave (2 MFMA row-groups)
#define BROWS 256              // rows per block (8 waves x 32)
#define RBLOCKS  (L_TOK / 32)  // 1024 refine blocks
#define EBLK  (NE / 4)         // prep blocks doing e rows
#define ZBLK  (L_TOK / 4)      // prep blocks doing z rows

#define ASCALE  -4194304.0f    // -2^22: A-fragment pre-scale (exact pow2)
#define KBIAS_F  32768.0f      // 2^15 bias as constant MFMA C operand.
                               // esq*2^21 <= 0.5 acc-units: dropped from sieve;
                               // exact esq32 still used in rescore.
#define KMASK    0xFFFFF000u   // float-bit key: top 20 bits of acc, idx in low 12
#define QDU      168u          // prune window in ACC-UNITS (160 proven + 8 esq-drop)
// Window in key-steps is computed adaptively in vq_refine from minqi's binade:
// masked-key granularity = 2^12 ulps = 2^(exp-138) acc-units.  acc in ~(8.1k,
// 57.4k) by C-S -> exp in {140,141,142} -> step {4,8,16} units -> steps
// qd = (QDU >> (exp-138)) + 1 = {43,22,11} covers {172,176,176} >= QDU units.
// Crossing into a coarser binade above only widens per-step coverage.

typedef unsigned short ushort_t;
typedef __attribute__((ext_vector_type(8))) short bf16x8;
typedef __attribute__((ext_vector_type(4))) float f32x4;

// ---- ws layout (bytes) ----
#define WS_EHI   0u                                  // 2 MB   e bf16(RNE) permuted
#define WS_ESQ32 (2u<<20)                            // 64 KB  esq np-exact fp32
#define WS_ESQS  ((2u<<20) + (64u<<10))              // 64 KB  (reserved, unused)
#define WS_ZSQ32 ((2u<<20) + (128u<<10))             // 128 KB zsq np-exact fp32
#define WS_CAND  ((2u<<20) + (256u<<10))             // 4 MB   candkeys[L][8][4] u32
#define WS_PART  ((6u<<20) + (256u<<10))             // 8 KB   loss partials (1024 dbl)

__device__ __forceinline__ ushort_t bf16_rne(float v) {
  unsigned u = __float_as_uint(v);
  return (ushort_t)((u + 0x7fffu + ((u >> 16) & 1u)) >> 16);
}

// v_med3_u32: median(a,b,c). With b<=c this equals min(max(a,b),c) — the
// top-k insertion step; asked for directly since the compiler can't prove
// the K-ordering invariant.  (Proven safe: present in every passing run.)
__device__ __forceinline__ unsigned umed3(unsigned a, unsigned b, unsigned c) {
  unsigned d;
  asm("v_med3_u32 %0, %1, %2, %3" : "=v"(d) : "v"(a), "v"(b), "v"(c));
  return d;
}

// async global->LDS DMA, 16 B/lane (no VGPR round-trip; counts in vmcnt)
__device__ __forceinline__ void load_lds16(const ushort_t* g, ushort_t* l) {
  __builtin_amdgcn_global_load_lds(
      (const __attribute__((address_space(1))) void*)g,
      (__attribute__((address_space(3))) void*)l, 16, 0, 0);
}

// numpy pairwise_sum emulation for n=64 contiguous fp32 (scalar 8-acc path).
__device__ __forceinline__ float np_sum64(float a) {
  int j = threadIdx.x & 7;
  float r = __shfl(a, j);
  #pragma unroll
  for (int m = 1; m < 8; ++m) r += __shfl(a, j + 8 * m);
  float s0 = __shfl(r, 0), s1 = __shfl(r, 1), s2 = __shfl(r, 2), s3 = __shfl(r, 3);
  float s4 = __shfl(r, 4), s5 = __shfl(r, 5), s6 = __shfl(r, 6), s7 = __shfl(r, 7);
  return ((s0 + s1) + (s2 + s3)) + ((s4 + s5) + (s6 + s7));
}

// Fragment-permuted index (in ushorts) for element (n, k) — LDS staging order
// equals MFMA B-fragment consumption order (conflict-free ds_read_b128).
__device__ __forceinline__ int perm_off(int n, int k) {
  int tile = n >> 4, c = n & 15, s = k >> 5, q = (k >> 3) & 3, j = k & 7;
  return tile * 1024 + s * 512 + (q * 16 + c) * 8 + j;
}

// ---------------- kernel 1: combined prep (e rows, then z rows) --------------
__global__ __launch_bounds__(256) void vq_prep(const float* __restrict__ e,
                                               const float* __restrict__ z,
                                               ushort_t* __restrict__ ehi,
                                               float* __restrict__ esq32,
                                               float* __restrict__ zsq32) {
  int wave = threadIdx.x >> 6, lane = threadIdx.x & 63;
  if (blockIdx.x < EBLK) {
    int row = blockIdx.x * 4 + wave;          // one wave per embedding row
    float v = e[(size_t)row * D_DIM + lane];
    ehi[perm_off(row, lane)] = bf16_rne(v);
    float esq = np_sum64(v * v);              // numpy-bit-exact sum(e*e, axis=1)
    if (lane == 0) esq32[row] = esq;          // exact rescore only (sieve drops esq)
  } else {
    int row = (blockIdx.x - EBLK) * 4 + wave; // one wave per z row
    float v = z[(size_t)row * D_DIM + lane];
    float s = np_sum64(v * v);                // numpy-bit-exact sum(z*z, axis=1)
    if (lane == 0) zsq32[row] = s;
  }
}

// ---------------- kernel 2: fused distance + per-row top-k sieve -------------
// grid = dim3(GCHUNKS, L/BROWS) = 1024 blocks, block = 512 (8 waves x 32 rows)
// Staging: async global_load_lds DMA, double-buffered 16 KB chunks.
// acc = 2^21*(-2dot) + 2^15 (C = const 2^15). By C-S acc in ~(8.1k, 57k) > 0,
// so IEEE bits are order-monotone as u32 (across binades).
// Packed key: (float_bits(acc) & 0xFFFFF000) | n_local — plain C++ and|or
// (LLVM folds to v_and_or_b32; no cvt on the critical path).
// Per-lane top-2 -> per-row top-4 RAW KEYS per 2048-chunk -> candk[row][ch][4].
__global__ __launch_bounds__(512, 8) void vq_argmin(const float* __restrict__ z,
                                                    const ushort_t* __restrict__ ehi,
                                                    unsigned* __restrict__ candk) {
  __shared__ __align__(16) unsigned char smem[36864]; // dbuf 2x16KB;
  ushort_t* s_buf = (ushort_t*)smem;                  // merge: 256x36 words (36.9KB)

  const int tid = threadIdx.x;
  const int wave = tid >> 6, lane = tid & 63;
  const int q = lane >> 4, c = lane & 15;
  const int row0 = blockIdx.y * BROWS + wave * WROWS;
  const int nbase = blockIdx.x * NPB;

  // A fragments: two row-groups of 16, bf16(RNE) of -2^22*z in-register.
  bf16x8 zA[2][2];
  #pragma unroll
  for (int g = 0; g < 2; ++g) {
    const float* zr = z + (size_t)(row0 + g * 16 + c) * D_DIM;
    float4 a0 = *(const float4*)(zr + q * 8);
    float4 a1 = *(const float4*)(zr + q * 8 + 4);
    float4 a2 = *(const float4*)(zr + 32 + q * 8);
    float4 a3 = *(const float4*)(zr + 32 + q * 8 + 4);
    zA[g][0][0] = (short)bf16_rne(a0.x * ASCALE); zA[g][0][1] = (short)bf16_rne(a0.y * ASCALE);
    zA[g][0][2] = (short)bf16_rne(a0.z * ASCALE); zA[g][0][3] = (short)bf16_rne(a0.w * ASCALE);
    zA[g][0][4] = (short)bf16_rne(a1.x * ASCALE); zA[g][0][5] = (short)bf16_rne(a1.y * ASCALE);
    zA[g][0][6] = (short)bf16_rne(a1.z * ASCALE); zA[g][0][7] = (short)bf16_rne(a1.w * ASCALE);
    zA[g][1][0] = (short)bf16_rne(a2.x * ASCALE); zA[g][1][1] = (short)bf16_rne(a2.y * ASCALE);
    zA[g][1][2] = (short)bf16_rne(a2.z * ASCALE); zA[g][1][3] = (short)bf16_rne(a2.w * ASCALE);
    zA[g][1][4] = (short)bf16_rne(a3.x * ASCALE); zA[g][1][5] = (short)bf16_rne(a3.y * ASCALE);
    zA[g][1][6] = (short)bf16_rne(a3.z * ASCALE); zA[g][1][7] = (short)bf16_rne(a3.w * ASCALE);
  }

  const f32x4 cvec = {KBIAS_F, KBIAS_F, KBIAS_F, KBIAS_F}; // hoisted constant C

  // per-(rowgroup g, acc row r) top-2 packed-key tracking, K0 <= K1 invariant
  unsigned K0[2][4], K1[2][4];
  #pragma unroll
  for (int g = 0; g < 2; ++g)
    #pragma unroll
    for (int r = 0; r < 4; ++r) { K0[g][r] = 0xFFFFFFFFu; K1[g][r] = 0xFFFFFFFFu; }

  // prologue: async-stage chunk 0 into buf0 (2 DMA instructions per wave)
  {
    const ushort_t* g = ehi + (size_t)nbase * 64 + wave * 1024 + lane * 8;
    ushort_t* l = s_buf + wave * 1024 + lane * 8;
    load_lds16(g, l);
    load_lds16(g + 512, l + 512);
  }

  for (int cb = 0; cb < NCH; ++cb) {
    __syncthreads();   // vmcnt(0) waits loads(cb) — issued a compute-phase ago
    if (cb + 1 < NCH) {            // async-stage next chunk into the idle buffer
      int nnext = nbase + (cb + 1) * BN;
      const ushort_t* g = ehi + (size_t)nnext * 64 + wave * 1024 + lane * 8;
      ushort_t* l = s_buf + ((cb + 1) & 1) * 8192 + wave * 1024 + lane * 8;
      load_lds16(g, l);
      load_lds16(g + 512, l + 512);
    }
    const ushort_t* buf = s_buf + (cb & 1) * 8192;

    #pragma unroll
    for (int t = 0; t < BN / 16; ++t) {
      const bf16x8 bh0 = *(const bf16x8*)(buf + t * 1024 + lane * 8);
      const bf16x8 bh1 = *(const bf16x8*)(buf + t * 1024 + 512 + lane * 8);
      unsigned tcv = (((unsigned)(cb * 8 + t)) << 4) | (unsigned)c;  // n_local
      f32x4 acc0 = __builtin_amdgcn_mfma_f32_16x16x32_bf16(zA[0][0], bh0, cvec, 0, 0, 0);
      acc0 = __builtin_amdgcn_mfma_f32_16x16x32_bf16(zA[0][1], bh1, acc0, 0, 0, 0);
      f32x4 acc1 = __builtin_amdgcn_mfma_f32_16x16x32_bf16(zA[1][0], bh0, cvec, 0, 0, 0);
      acc1 = __builtin_amdgcn_mfma_f32_16x16x32_bf16(zA[1][1], bh1, acc1, 0, 0, 0);
      #pragma unroll
      for (int r = 0; r < 4; ++r) {
        unsigned pk = (__float_as_uint(acc0[r]) & KMASK) | tcv;  // and_or key
        K1[0][r] = umed3(pk, K0[0][r], K1[0][r]);
        K0[0][r] = min(pk, K0[0][r]);
      }
      #pragma unroll
      for (int r = 0; r < 4; ++r) {
        unsigned pk = (__float_as_uint(acc1[r]) & KMASK) | tcv;
        K1[1][r] = umed3(pk, K0[1][r], K1[1][r]);
        K0[1][r] = min(pk, K0[1][r]);
      }
    }
  }

  // merge 16 lanes' top-2 -> per-row top-4 keys (row stride 36 words: breaks
  // the all-lanes-same-bank-group pattern of stride 32)
  __syncthreads();
  unsigned* s_k = (unsigned*)smem;             // [256 rows][36 words]
  #pragma unroll
  for (int g = 0; g < 2; ++g)
    #pragma unroll
    for (int r = 0; r < 4; ++r) {
      int rowidx = wave * WROWS + g * 16 + q * 4 + r;  // C layout: row = q*4 + reg
      int base = rowidx * 36 + c * 2;
      s_k[base + 0] = K0[g][r]; s_k[base + 1] = K1[g][r];
    }
  __syncthreads();
  if (tid < BROWS) {
    unsigned M0 = 0xFFFFFFFFu, M1 = 0xFFFFFFFFu, M2 = 0xFFFFFFFFu, M3 = 0xFFFFFFFFu;
    const uint4* sv = (const uint4*)(s_k + tid * 36);
    #pragma unroll
    for (int v4 = 0; v4 < 8; ++v4) {
      uint4 kk = sv[v4];
      unsigned vals[4] = {kk.x, kk.y, kk.z, kk.w};
      #pragma unroll
      for (int u = 0; u < 4; ++u) {
        unsigned v = vals[u];
        M3 = umed3(v, M2, M3);
        M2 = umed3(v, M1, M2);
        M1 = umed3(v, M0, M1);
        M0 = min(v, M0);
      }
    }
    int grow = blockIdx.y * BROWS + tid;
    unsigned* cp = candk + ((size_t)grow * GCHUNKS + blockIdx.x) * 4;
    cp[0] = M0; cp[1] = M1; cp[2] = M2; cp[3] = M3;    // raw keys (fbits|n_local)
  }
}

// ------- kernel 3: key-pruned np-fp32-exact rescore, outputs ----------------
// grid = L/32 blocks, block 512 (8 waves); wave: 4 rows, 32 cand-groups x 2
// lanes.  qi = key>>12 = float bits >> 12 (20-bit, monotone in d).  minqi is
// reduced directly (no pack — 20-bit qi<<14 would overflow).  Window in steps
// derived from minqi's binade; see QDU comment at top.
__global__ __launch_bounds__(512, 6) void vq_refine(const float* __restrict__ z,
                                                    const float* __restrict__ e,
                                                    const float* __restrict__ esq32,
                                                    const float* __restrict__ zsq32,
                                                    const unsigned* __restrict__ candk,
                                                    float* __restrict__ out,
                                                    double* __restrict__ partials) {
  const int tid = threadIdx.x;
  const int wave = tid >> 6, lane = tid & 63;
  const int g = lane >> 1, s = lane & 1;      // 32 cand-groups x 2 lanes
  __shared__ double sp[8];
  double wl = 0.0;                             // per-lane loss partial
  for (int it = 0; it < 4; ++it) {
    int row = blockIdx.x * 32 + wave * 4 + it;
    float zf = z[(size_t)row * D_DIM + lane];
    float zsqv = zsq32[row];
    unsigned k = candk[(size_t)row * 32 + g];  // coalesced 128 B per row
    unsigned qi = k >> 12;                     // 20-bit float-hi-bits rank
    unsigned n  = ((unsigned)(g >> 2)) * (unsigned)NPB + (k & 4095u);
    unsigned m = qi;                           // reduce qi directly for minqi
    #pragma unroll
    for (int o = 1; o < 64; o <<= 1) m = min(m, (unsigned)__shfl_xor((int)m, o));
    // adaptive window: exp = m>>11 (sign=0); step = 2^(exp-138) acc-units
    unsigned shift = (m >> 11) - 138u;         // in {2,3,4} for reachable accs
    unsigned qd = (QDU >> shift) + 1u;         // covers >= QDU acc-units
    bool part = qi <= m + qd;
    unsigned long long key = ~0ull;
    if (part) {                                // both lanes of a pair agree
      const float4* ep = (const float4*)(e + (size_t)n * D_DIM + s * 32);
      const float4* zp = (const float4*)(z + (size_t)row * D_DIM + s * 32);
      double da = 0.0, db = 0.0, dc = 0.0, dd = 0.0;
      #pragma unroll
      for (int h = 0; h < 2; ++h) {
        float4 e0 = ep[h * 4 + 0], e1 = ep[h * 4 + 1];
        float4 e2 = ep[h * 4 + 2], e3 = ep[h * 4 + 3];
        float4 z0 = zp[h * 4 + 0], z1 = zp[h * 4 + 1];
        float4 z2 = zp[h * 4 + 2], z3 = zp[h * 4 + 3];
        da = fma((double)e0.x, (double)z0.x, da); da = fma((double)e0.y, (double)z0.y, da);
        da = fma((double)e0.z, (double)z0.z, da); da = fma((double)e0.w, (double)z0.w, da);
        db = fma((double)e1.x, (double)z1.x, db); db = fma((double)e1.y, (double)z1.y, db);
        db = fma((double)e1.z, (double)z1.z, db); db = fma((double)e1.w, (double)z1.w, db);
        dc = fma((double)e2.x, (double)z2.x, dc); dc = fma((double)e2.y, (double)z2.y, dc);
        dc = fma((double)e2.z, (double)z2.z, dc); dc = fma((double)e2.w, (double)z2.w, dc);
        dd = fma((double)e3.x, (double)z3.x, dd); dd = fma((double)e3.y, (double)z3.y, dd);
        dd = fma((double)e3.z, (double)z3.z, dd); dd = fma((double)e3.w, (double)z3.w, dd);
      }
      double dot = (da + db) + (dc + dd);
      dot += __shfl_xor(dot, 1);               // pair-mate has same `part`
      // emulate np fp32: d = fl32( fl32(zsq + esq) - fl32(2*dot) )
      float t2 = (float)(2.0 * dot);
      float T1 = zsqv + esq32[n];
      float d  = T1 - t2;                      // d ~ 64 > 0: bits are monotone
      key  = ((unsigned long long)__float_as_uint(d) << 14) | n;  // tie: lower n
    }
    #pragma unroll
    for (int o = 2; o <= 32; o <<= 1) {        // pair-mates equal; 5 steps
      unsigned long long ok = __shfl_xor(key, o);
      key = ok < key ? ok : key;
    }
    int win = (int)(key & 16383u);
    // outputs (element layout; whole wave)
    float be = e[(size_t)win * D_DIM + lane];
    out[(size_t)row * D_DIM + lane] = zf + (be - zf);   // fp32 op-order ST
    if (lane == 0) out[(size_t)L_TOK * D_DIM + 1 + row] = (float)win;
    double dd2 = (double)be - (double)zf;
    wl += dd2 * dd2;                           // per-lane loss contribution
  }
  #pragma unroll
  for (int o = 32; o; o >>= 1) wl += __shfl_xor(wl, o);
  if (lane == 0) sp[wave] = wl;
  __syncthreads();
  if (tid == 0) {
    double t = 0.0;
    #pragma unroll
    for (int w = 0; w < 8; ++w) t += sp[w];
    partials[blockIdx.x] = t;
  }
}

// ---------------- kernel 4: finalize loss (1024 partials) --------------------
__global__ __launch_bounds__(512) void vq_loss(const double* __restrict__ partials,
                                               float* __restrict__ out) {
  int tid = threadIdx.x;
  double v = partials[tid] + partials[tid + 512];
  #pragma unroll
  for (int o = 32; o; o >>= 1) v += __shfl_xor(v, o);
  __shared__ double sp[8];
  if ((tid & 63) == 0) sp[tid >> 6] = v;
  __syncthreads();
  if (tid == 0) {
    double tot = 0.0;
    #pragma unroll
    for (int w = 0; w < 8; ++w) tot += sp[w];
    // loss = beta*mean + mean = 1.25 * mean((z_q - z)^2)
    out[(size_t)L_TOK * D_DIM] = (float)(1.25 * tot / (double)((size_t)L_TOK * D_DIM));
  }
}

extern "C" void kernel_launch(void* const* d_in, const int* in_sizes, int n_in,
                              void* d_out, int out_size, void* d_ws, size_t ws_size,
                              hipStream_t stream) {
  const float* z = (const float*)d_in[0];       // (32768, 64) fp32
  const float* e = (const float*)d_in[1];       // (16384, 64) fp32
  float* out = (float*)d_out;                   // [z_q_st | loss | indices-as-f32]
  char* ws = (char*)d_ws;                       // needs ~6.3 MB

  ushort_t* ehi   = (ushort_t*)(ws + WS_EHI);
  float*    esq32 = (float*)(ws + WS_ESQ32);
  float*    zsq32 = (float*)(ws + WS_ZSQ32);
  unsigned* candk = (unsigned*)(ws + WS_CAND);
  double*   parts = (double*)(ws + WS_PART);

  vq_prep<<<EBLK + ZBLK, 256, 0, stream>>>(e, z, ehi, esq32, zsq32);
  vq_argmin<<<dim3(GCHUNKS, L_TOK / BROWS), 512, 0, stream>>>(z, ehi, candk);
  vq_refine<<<RBLOCKS, 512, 0, stream>>>(z, e, esq32, zsq32, candk, out, parts);
  vq_loss<<<1, 512, 0, stream>>>(parts, out);
}

// Round 6
// 204.959 us; speedup vs baseline: 1.0744x; 1.0744x over previous
//
#include <hip/hip_runtime.h>
#include <cstdint>
#include <cstddef>

// Problem constants (VectorQuantizer: L=32768, D=64, N_E=16384, beta=0.25)
#define L_TOK 32768
#define D_DIM 64
#define NE    16384
#define GCHUNKS 8              // N split across grid (8 -> 8192 waves total)
#define NPB   (NE / GCHUNKS)   // 2048 n per block
#define BN    128              // n per LDS stage chunk (double-buffered)
#define NCH   (NPB / BN)       // 16 chunks per block
#define WROWS 32               // rows per wave (2 MFMA row-groups)
#define BROWS 256              // rows per block (8 waves x 32)
#define RBLOCKS  (L_TOK / 32)  // 1024 refine blocks
#define EBLK  (NE / 4)         // prep blocks (e rows only; zsq fused into refine)

#define ASCALE  -4194304.0f    // -2^22: A-fragment pre-scale (exact pow2)
#define KBIAS_F  32768.0f      // 2^15 bias as constant MFMA C operand.
                               // esq*2^21 <= 0.5 qi-units: dropped from sieve;
                               // exact esq32 still used in rescore.
#define QDELTA   168u          // prune window in qi units (160 proven + 8 esq-drop)

typedef unsigned short ushort_t;
typedef __attribute__((ext_vector_type(8))) short bf16x8;
typedef __attribute__((ext_vector_type(4))) float f32x4;

// ---- ws layout (bytes) ----
#define WS_EHI   0u                                  // 2 MB   e bf16(RNE) permuted
#define WS_ESQ32 (2u<<20)                            // 64 KB  esq np-exact fp32
#define WS_ESQS  ((2u<<20) + (64u<<10))              // 64 KB  (reserved, unused)
#define WS_ZSQ32 ((2u<<20) + (128u<<10))             // 128 KB (reserved, unused)
#define WS_CAND  ((2u<<20) + (256u<<10))             // 4 MB   candkeys[L][8][4] u32
#define WS_PART  ((6u<<20) + (256u<<10))             // 8 KB   loss partials (1024 dbl)

__device__ __forceinline__ ushort_t bf16_rne(float v) {
  unsigned u = __float_as_uint(v);
  return (ushort_t)((u + 0x7fffu + ((u >> 16) & 1u)) >> 16);
}

// v_med3_u32: median(a,b,c). With b<=c this equals min(max(a,b),c) — the
// top-k insertion step; asked for directly since the compiler can't prove
// the K-ordering invariant.  (Proven safe: present in every passing run.)
__device__ __forceinline__ unsigned umed3(unsigned a, unsigned b, unsigned c) {
  unsigned d;
  asm("v_med3_u32 %0, %1, %2, %3" : "=v"(d) : "v"(a), "v"(b), "v"(c));
  return d;
}

// async global->LDS DMA, 16 B/lane (no VGPR round-trip; counts in vmcnt)
__device__ __forceinline__ void load_lds16(const ushort_t* g, ushort_t* l) {
  __builtin_amdgcn_global_load_lds(
      (const __attribute__((address_space(1))) void*)g,
      (__attribute__((address_space(3))) void*)l, 16, 0, 0);
}

// numpy pairwise_sum emulation for n=64 contiguous fp32 (scalar 8-acc path).
// Wave-wide: all 64 lanes must hold the row's elements (lane = k index).
__device__ __forceinline__ float np_sum64(float a) {
  int j = threadIdx.x & 7;
  float r = __shfl(a, j);
  #pragma unroll
  for (int m = 1; m < 8; ++m) r += __shfl(a, j + 8 * m);
  float s0 = __shfl(r, 0), s1 = __shfl(r, 1), s2 = __shfl(r, 2), s3 = __shfl(r, 3);
  float s4 = __shfl(r, 4), s5 = __shfl(r, 5), s6 = __shfl(r, 6), s7 = __shfl(r, 7);
  return ((s0 + s1) + (s2 + s3)) + ((s4 + s5) + (s6 + s7));
}

// Fragment-permuted index (in ushorts) for element (n, k) — LDS staging order
// equals MFMA B-fragment consumption order (conflict-free ds_read_b128).
__device__ __forceinline__ int perm_off(int n, int k) {
  int tile = n >> 4, c = n & 15, s = k >> 5, q = (k >> 3) & 3, j = k & 7;
  return tile * 1024 + s * 512 + (q * 16 + c) * 8 + j;
}

// ---------------- kernel 1: prep (e rows only) -------------------------------
// zsq is computed inside vq_refine (identical np_sum64 on identical loads ->
// bit-exact), so prep no longer touches z at all: 4096 blocks, not 12288.
__global__ __launch_bounds__(256) void vq_prep(const float* __restrict__ e,
                                               ushort_t* __restrict__ ehi,
                                               float* __restrict__ esq32) {
  int wave = threadIdx.x >> 6, lane = threadIdx.x & 63;
  int row = blockIdx.x * 4 + wave;            // one wave per embedding row
  float v = e[(size_t)row * D_DIM + lane];
  ehi[perm_off(row, lane)] = bf16_rne(v);
  float esq = np_sum64(v * v);                // numpy-bit-exact sum(e*e, axis=1)
  if (lane == 0) esq32[row] = esq;            // exact rescore only (sieve drops esq)
}

// ---------------- kernel 2: fused distance + per-row top-k sieve -------------
// grid = dim3(GCHUNKS, L/BROWS) = 1024 blocks, block = 512 (8 waves x 32 rows)
// Staging: async global_load_lds DMA, double-buffered 16 KB chunks.
// acc = 2^21*(-2dot) + 2^15 (C = const 2^15). By C-S acc in ~(8.1k, 57k) > 0,
// trunc keys order-correct.  Packed key: (trunc(acc) << 12) | (tile*16+c).
// Per-lane top-2 -> per-row top-4 RAW KEYS per 2048-chunk -> candk[row][ch][4].
// (Integer keys are the proven floor: 4 VALU/insert, no spill at the 64-VGPR
// cap from launch_bounds(512,8) — float-bit keys spilled: r5 FETCH/WRITE 2-6x.)
__global__ __launch_bounds__(512, 8) void vq_argmin(const float* __restrict__ z,
                                                    const ushort_t* __restrict__ ehi,
                                                    unsigned* __restrict__ candk) {
  __shared__ __align__(16) unsigned char smem[36864]; // dbuf 2x16KB;
  ushort_t* s_buf = (ushort_t*)smem;                  // merge: 256x36 words (36.9KB)

  const int tid = threadIdx.x;
  const int wave = tid >> 6, lane = tid & 63;
  const int q = lane >> 4, c = lane & 15;
  const int row0 = blockIdx.y * BROWS + wave * WROWS;
  const int nbase = blockIdx.x * NPB;

  // A fragments: two row-groups of 16, bf16(RNE) of -2^22*z in-register.
  bf16x8 zA[2][2];
  #pragma unroll
  for (int g = 0; g < 2; ++g) {
    const float* zr = z + (size_t)(row0 + g * 16 + c) * D_DIM;
    float4 a0 = *(const float4*)(zr + q * 8);
    float4 a1 = *(const float4*)(zr + q * 8 + 4);
    float4 a2 = *(const float4*)(zr + 32 + q * 8);
    float4 a3 = *(const float4*)(zr + 32 + q * 8 + 4);
    zA[g][0][0] = (short)bf16_rne(a0.x * ASCALE); zA[g][0][1] = (short)bf16_rne(a0.y * ASCALE);
    zA[g][0][2] = (short)bf16_rne(a0.z * ASCALE); zA[g][0][3] = (short)bf16_rne(a0.w * ASCALE);
    zA[g][0][4] = (short)bf16_rne(a1.x * ASCALE); zA[g][0][5] = (short)bf16_rne(a1.y * ASCALE);
    zA[g][0][6] = (short)bf16_rne(a1.z * ASCALE); zA[g][0][7] = (short)bf16_rne(a1.w * ASCALE);
    zA[g][1][0] = (short)bf16_rne(a2.x * ASCALE); zA[g][1][1] = (short)bf16_rne(a2.y * ASCALE);
    zA[g][1][2] = (short)bf16_rne(a2.z * ASCALE); zA[g][1][3] = (short)bf16_rne(a2.w * ASCALE);
    zA[g][1][4] = (short)bf16_rne(a3.x * ASCALE); zA[g][1][5] = (short)bf16_rne(a3.y * ASCALE);
    zA[g][1][6] = (short)bf16_rne(a3.z * ASCALE); zA[g][1][7] = (short)bf16_rne(a3.w * ASCALE);
  }

  const f32x4 cvec = {KBIAS_F, KBIAS_F, KBIAS_F, KBIAS_F}; // hoisted constant C

  // per-(rowgroup g, acc row r) top-2 packed-key tracking, K0 <= K1 invariant
  unsigned K0[2][4], K1[2][4];
  #pragma unroll
  for (int g = 0; g < 2; ++g)
    #pragma unroll
    for (int r = 0; r < 4; ++r) { K0[g][r] = 0xFFFFFFFFu; K1[g][r] = 0xFFFFFFFFu; }

  // prologue: async-stage chunk 0 into buf0 (2 DMA instructions per wave)
  {
    const ushort_t* g = ehi + (size_t)nbase * 64 + wave * 1024 + lane * 8;
    ushort_t* l = s_buf + wave * 1024 + lane * 8;
    load_lds16(g, l);
    load_lds16(g + 512, l + 512);
  }

  for (int cb = 0; cb < NCH; ++cb) {
    __syncthreads();   // vmcnt(0) waits loads(cb) — issued a compute-phase ago
    if (cb + 1 < NCH) {            // async-stage next chunk into the idle buffer
      int nnext = nbase + (cb + 1) * BN;
      const ushort_t* g = ehi + (size_t)nnext * 64 + wave * 1024 + lane * 8;
      ushort_t* l = s_buf + ((cb + 1) & 1) * 8192 + wave * 1024 + lane * 8;
      load_lds16(g, l);
      load_lds16(g + 512, l + 512);
    }
    const ushort_t* buf = s_buf + (cb & 1) * 8192;

    #pragma unroll
    for (int t = 0; t < BN / 16; ++t) {
      const bf16x8 bh0 = *(const bf16x8*)(buf + t * 1024 + lane * 8);
      const bf16x8 bh1 = *(const bf16x8*)(buf + t * 1024 + 512 + lane * 8);
      unsigned tcv = (((unsigned)(cb * 8 + t)) << 4) | (unsigned)c;  // n_local
      f32x4 acc0 = __builtin_amdgcn_mfma_f32_16x16x32_bf16(zA[0][0], bh0, cvec, 0, 0, 0);
      acc0 = __builtin_amdgcn_mfma_f32_16x16x32_bf16(zA[0][1], bh1, acc0, 0, 0, 0);
      f32x4 acc1 = __builtin_amdgcn_mfma_f32_16x16x32_bf16(zA[1][0], bh0, cvec, 0, 0, 0);
      acc1 = __builtin_amdgcn_mfma_f32_16x16x32_bf16(zA[1][1], bh1, acc1, 0, 0, 0);
      #pragma unroll
      for (int r = 0; r < 4; ++r) {
        unsigned pk = (((unsigned)acc0[r]) << 12) | tcv;   // cvt + lshl_or
        K1[0][r] = umed3(pk, K0[0][r], K1[0][r]);
        K0[0][r] = min(pk, K0[0][r]);
      }
      #pragma unroll
      for (int r = 0; r < 4; ++r) {
        unsigned pk = (((unsigned)acc1[r]) << 12) | tcv;
        K1[1][r] = umed3(pk, K0[1][r], K1[1][r]);
        K0[1][r] = min(pk, K0[1][r]);
      }
    }
  }

  // merge 16 lanes' top-2 -> per-row top-4 keys (row stride 36 words: breaks
  // the all-lanes-same-bank-group pattern of stride 32)
  __syncthreads();
  unsigned* s_k = (unsigned*)smem;             // [256 rows][36 words]
  #pragma unroll
  for (int g = 0; g < 2; ++g)
    #pragma unroll
    for (int r = 0; r < 4; ++r) {
      int rowidx = wave * WROWS + g * 16 + q * 4 + r;  // C layout: row = q*4 + reg
      int base = rowidx * 36 + c * 2;
      s_k[base + 0] = K0[g][r]; s_k[base + 1] = K1[g][r];
    }
  __syncthreads();
  if (tid < BROWS) {
    unsigned M0 = 0xFFFFFFFFu, M1 = 0xFFFFFFFFu, M2 = 0xFFFFFFFFu, M3 = 0xFFFFFFFFu;
    const uint4* sv = (const uint4*)(s_k + tid * 36);
    #pragma unroll
    for (int v4 = 0; v4 < 8; ++v4) {
      uint4 kk = sv[v4];
      unsigned vals[4] = {kk.x, kk.y, kk.z, kk.w};
      #pragma unroll
      for (int u = 0; u < 4; ++u) {
        unsigned v = vals[u];
        M3 = umed3(v, M2, M3);
        M2 = umed3(v, M1, M2);
        M1 = umed3(v, M0, M1);
        M0 = min(v, M0);
      }
    }
    int grow = blockIdx.y * BROWS + tid;
    unsigned* cp = candk + ((size_t)grow * GCHUNKS + blockIdx.x) * 4;
    cp[0] = M0; cp[1] = M1; cp[2] = M2; cp[3] = M3;    // raw keys (qi<<12|n_local)
  }
}

// ------- kernel 3: key-pruned np-fp32-exact rescore, outputs ----------------
// grid = L/32 blocks, block 512 (8 waves); wave: 4 rows, 32 cand-groups x 2
// lanes.  zsq computed in-wave (np_sum64 of the already-loaded z row —
// bit-identical to the old prep path).  Per-row: one coalesced 128B candk
// read, 6-step u32 prune reduce, pruned fp64 dot, 5-step 64-bit key reduce.
__global__ __launch_bounds__(512, 6) void vq_refine(const float* __restrict__ z,
                                                    const float* __restrict__ e,
                                                    const float* __restrict__ esq32,
                                                    const unsigned* __restrict__ candk,
                                                    float* __restrict__ out,
                                                    double* __restrict__ partials) {
  const int tid = threadIdx.x;
  const int wave = tid >> 6, lane = tid & 63;
  const int g = lane >> 1, s = lane & 1;      // 32 cand-groups x 2 lanes
  __shared__ double sp[8];
  double wl = 0.0;                             // per-lane loss partial
  for (int it = 0; it < 4; ++it) {
    int row = blockIdx.x * 32 + wave * 4 + it;
    float zf = z[(size_t)row * D_DIM + lane];
    float zsqv = np_sum64(zf * zf);            // numpy-bit-exact sum(z*z) in-wave
    unsigned k = candk[(size_t)row * 32 + g];  // coalesced 128 B per row
    unsigned qi = k >> 12;
    unsigned n  = ((unsigned)(g >> 2)) * (unsigned)NPB + (k & 4095u);
    unsigned gkey = (qi << 14) | n;            // globally ordered (qi, then n)
    unsigned m = gkey;
    #pragma unroll
    for (int o = 1; o < 64; o <<= 1) m = min(m, (unsigned)__shfl_xor((int)m, o));
    unsigned minqi = m >> 14;
    bool part = qi <= minqi + QDELTA;
    unsigned long long key = ~0ull;
    if (part) {                                // both lanes of a pair agree
      const float4* ep = (const float4*)(e + (size_t)n * D_DIM + s * 32);
      const float4* zp = (const float4*)(z + (size_t)row * D_DIM + s * 32);
      double da = 0.0, db = 0.0, dc = 0.0, dd = 0.0;
      #pragma unroll
      for (int h = 0; h < 2; ++h) {
        float4 e0 = ep[h * 4 + 0], e1 = ep[h * 4 + 1];
        float4 e2 = ep[h * 4 + 2], e3 = ep[h * 4 + 3];
        float4 z0 = zp[h * 4 + 0], z1 = zp[h * 4 + 1];
        float4 z2 = zp[h * 4 + 2], z3 = zp[h * 4 + 3];
        da = fma((double)e0.x, (double)z0.x, da); da = fma((double)e0.y, (double)z0.y, da);
        da = fma((double)e0.z, (double)z0.z, da); da = fma((double)e0.w, (double)z0.w, da);
        db = fma((double)e1.x, (double)z1.x, db); db = fma((double)e1.y, (double)z1.y, db);
        db = fma((double)e1.z, (double)z1.z, db); db = fma((double)e1.w, (double)z1.w, db);
        dc = fma((double)e2.x, (double)z2.x, dc); dc = fma((double)e2.y, (double)z2.y, dc);
        dc = fma((double)e2.z, (double)z2.z, dc); dc = fma((double)e2.w, (double)z2.w, dc);
        dd = fma((double)e3.x, (double)z3.x, dd); dd = fma((double)e3.y, (double)z3.y, dd);
        dd = fma((double)e3.z, (double)z3.z, dd); dd = fma((double)e3.w, (double)z3.w, dd);
      }
      double dot = (da + db) + (dc + dd);
      dot += __shfl_xor(dot, 1);               // pair-mate has same `part`
      // emulate np fp32: d = fl32( fl32(zsq + esq) - fl32(2*dot) )
      float t2 = (float)(2.0 * dot);
      float T1 = zsqv + esq32[n];
      float d  = T1 - t2;                      // d ~ 64 > 0: bits are monotone
      key  = ((unsigned long long)__float_as_uint(d) << 14) | n;  // tie: lower n
    }
    #pragma unroll
    for (int o = 2; o <= 32; o <<= 1) {        // pair-mates equal; 5 steps
      unsigned long long ok = __shfl_xor(key, o);
      key = ok < key ? ok : key;
    }
    int win = (int)(key & 16383u);
    // outputs (element layout; whole wave)
    float be = e[(size_t)win * D_DIM + lane];
    out[(size_t)row * D_DIM + lane] = zf + (be - zf);   // fp32 op-order ST
    if (lane == 0) out[(size_t)L_TOK * D_DIM + 1 + row] = (float)win;
    double dd2 = (double)be - (double)zf;
    wl += dd2 * dd2;                           // per-lane loss contribution
  }
  #pragma unroll
  for (int o = 32; o; o >>= 1) wl += __shfl_xor(wl, o);
  if (lane == 0) sp[wave] = wl;
  __syncthreads();
  if (tid == 0) {
    double t = 0.0;
    #pragma unroll
    for (int w = 0; w < 8; ++w) t += sp[w];
    partials[blockIdx.x] = t;
  }
}

// ---------------- kernel 4: finalize loss (1024 partials) --------------------
__global__ __launch_bounds__(512) void vq_loss(const double* __restrict__ partials,
                                               float* __restrict__ out) {
  int tid = threadIdx.x;
  double v = partials[tid] + partials[tid + 512];
  #pragma unroll
  for (int o = 32; o; o >>= 1) v += __shfl_xor(v, o);
  __shared__ double sp[8];
  if ((tid & 63) == 0) sp[tid >> 6] = v;
  __syncthreads();
  if (tid == 0) {
    double tot = 0.0;
    #pragma unroll
    for (int w = 0; w < 8; ++w) tot += sp[w];
    // loss = beta*mean + mean = 1.25 * mean((z_q - z)^2)
    out[(size_t)L_TOK * D_DIM] = (float)(1.25 * tot / (double)((size_t)L_TOK * D_DIM));
  }
}

extern "C" void kernel_launch(void* const* d_in, const int* in_sizes, int n_in,
                              void* d_out, int out_size, void* d_ws, size_t ws_size,
                              hipStream_t stream) {
  const float* z = (const float*)d_in[0];       // (32768, 64) fp32
  const float* e = (const float*)d_in[1];       // (16384, 64) fp32
  float* out = (float*)d_out;                   // [z_q_st | loss | indices-as-f32]
  char* ws = (char*)d_ws;                       // needs ~6.3 MB

  ushort_t* ehi   = (ushort_t*)(ws + WS_EHI);
  float*    esq32 = (float*)(ws + WS_ESQ32);
  unsigned* candk = (unsigned*)(ws + WS_CAND);
  double*   parts = (double*)(ws + WS_PART);

  vq_prep<<<EBLK, 256, 0, stream>>>(e, ehi, esq32);
  vq_argmin<<<dim3(GCHUNKS, L_TOK / BROWS), 512, 0, stream>>>(z, ehi, candk);
  vq_refine<<<RBLOCKS, 512, 0, stream>>>(z, e, esq32, candk, out, parts);
  vq_loss<<<1, 512, 0, stream>>>(parts, out);
}

// Round 7
// 185.248 us; speedup vs baseline: 1.1887x; 1.1064x over previous
//
#include <hip/hip_runtime.h>
#include <cstdint>
#include <cstddef>

// Problem constants (VectorQuantizer: L=32768, D=64, N_E=16384, beta=0.25)
#define L_TOK 32768
#define D_DIM 64
#define NE    16384
#define GCHUNKS 8              // N split across grid (8 -> 8192 waves total)
#define NPB   (NE / GCHUNKS)   // 2048 n per block
#define BN    128              // n per LDS stage chunk (double-buffered)
#define NCH   (NPB / BN)       // 16 chunks per block
#define WROWS 32               // rows per wave (2 MFMA row-groups)
#define BROWS 256              // rows per block (8 waves x 32)
#define RBLOCKS  (L_TOK / 32)  // 1024 refine blocks
#define EBLK  (NE / 4)         // prep blocks doing e rows
#define ZBLK  (L_TOK / 4)      // prep blocks doing z rows

#define ASCALE  -4194304.0f    // -2^22: A-fragment pre-scale (exact pow2)
#define KBIAS_F  32768.0f      // 2^15 bias as constant MFMA C operand.
                               // esq*2^21 <= 0.5 acc-units: dropped from sieve;
                               // exact esq32 still used in rescore.
#define KMASK    0xFFFFF000u   // float-bit key: top 20 bits of acc, idx in low 12
#define QDU      168u          // prune window in ACC-UNITS (160 proven + 8 esq-drop)
// Window in key-steps is computed adaptively in vq_refine from minqi's binade:
// masked-key granularity = 2^12 ulps = 2^(exp-138) acc-units.  acc in ~(10k,
// 57k) by C-S -> exp in {140,141,142} -> step {4,8,16} units -> steps
// qd = (QDU >> (exp-138)) + 1 = {43,22,11} covers {172,176,176} >= QDU units.
// (Formula is conservative for any exp >= 138.)  This exact scheme passed
// refcheck in r5 (absmax 0); r5's regression was argmin scratch spill, not
// correctness.

typedef unsigned short ushort_t;
typedef __attribute__((ext_vector_type(8))) short bf16x8;
typedef __attribute__((ext_vector_type(4))) float f32x4;

// ---- ws layout (bytes) ----
#define WS_EHI   0u                                  // 2 MB   e bf16(RNE) permuted
#define WS_ESQ32 (2u<<20)                            // 64 KB  esq np-exact fp32
#define WS_ESQS  ((2u<<20) + (64u<<10))              // 64 KB  (reserved, unused)
#define WS_ZSQ32 ((2u<<20) + (128u<<10))             // 128 KB zsq np-exact fp32
#define WS_CAND  ((2u<<20) + (256u<<10))             // 4 MB   candkeys[L][8][4] u32
#define WS_PART  ((6u<<20) + (256u<<10))             // 8 KB   loss partials (1024 dbl)

__device__ __forceinline__ ushort_t bf16_rne(float v) {
  unsigned u = __float_as_uint(v);
  return (ushort_t)((u + 0x7fffu + ((u >> 16) & 1u)) >> 16);
}

// v_med3_u32: median(a,b,c). With b<=c this equals min(max(a,b),c) — the
// top-k insertion step; asked for directly since the compiler can't prove
// the K-ordering invariant.  (Proven safe: present in every passing run.)
__device__ __forceinline__ unsigned umed3(unsigned a, unsigned b, unsigned c) {
  unsigned d;
  asm("v_med3_u32 %0, %1, %2, %3" : "=v"(d) : "v"(a), "v"(b), "v"(c));
  return d;
}

// async global->LDS DMA, 16 B/lane (no VGPR round-trip; counts in vmcnt)
__device__ __forceinline__ void load_lds16(const ushort_t* g, ushort_t* l) {
  __builtin_amdgcn_global_load_lds(
      (const __attribute__((address_space(1))) void*)g,
      (__attribute__((address_space(3))) void*)l, 16, 0, 0);
}

// numpy pairwise_sum emulation for n=64 contiguous fp32 (scalar 8-acc path).
__device__ __forceinline__ float np_sum64(float a) {
  int j = threadIdx.x & 7;
  float r = __shfl(a, j);
  #pragma unroll
  for (int m = 1; m < 8; ++m) r += __shfl(a, j + 8 * m);
  float s0 = __shfl(r, 0), s1 = __shfl(r, 1), s2 = __shfl(r, 2), s3 = __shfl(r, 3);
  float s4 = __shfl(r, 4), s5 = __shfl(r, 5), s6 = __shfl(r, 6), s7 = __shfl(r, 7);
  return ((s0 + s1) + (s2 + s3)) + ((s4 + s5) + (s6 + s7));
}

// Fragment-permuted index (in ushorts) for element (n, k) — LDS staging order
// equals MFMA B-fragment consumption order (conflict-free ds_read_b128).
__device__ __forceinline__ int perm_off(int n, int k) {
  int tile = n >> 4, c = n & 15, s = k >> 5, q = (k >> 3) & 3, j = k & 7;
  return tile * 1024 + s * 512 + (q * 16 + c) * 8 + j;
}

// ---------------- kernel 1: combined prep (e rows, then z rows) --------------
// zsq stays precomputed here (r6's fusion into refine cost ~7us: refine is
// latency-bound and the 16-deep shuffle chain serialized; prep's 49k waves
// hide it for free).
__global__ __launch_bounds__(256) void vq_prep(const float* __restrict__ e,
                                               const float* __restrict__ z,
                                               ushort_t* __restrict__ ehi,
                                               float* __restrict__ esq32,
                                               float* __restrict__ zsq32) {
  int wave = threadIdx.x >> 6, lane = threadIdx.x & 63;
  if (blockIdx.x < EBLK) {
    int row = blockIdx.x * 4 + wave;          // one wave per embedding row
    float v = e[(size_t)row * D_DIM + lane];
    ehi[perm_off(row, lane)] = bf16_rne(v);
    float esq = np_sum64(v * v);              // numpy-bit-exact sum(e*e, axis=1)
    if (lane == 0) esq32[row] = esq;          // exact rescore only (sieve drops esq)
  } else {
    int row = (blockIdx.x - EBLK) * 4 + wave; // one wave per z row
    float v = z[(size_t)row * D_DIM + lane];
    float s = np_sum64(v * v);                // numpy-bit-exact sum(z*z, axis=1)
    if (lane == 0) zsq32[row] = s;
  }
}

// ---------------- kernel 2: fused distance + per-row top-k sieve -------------
// grid = dim3(GCHUNKS, L/BROWS) = 1024 blocks, block = 512 (8 waves x 32 rows)
// Issue-saturated kernel (VALU 71% + MFMA 25% at the throttled clock): the
// sieve insert dominates.  Float-bit key cuts it 4->3 ops: acc > 0 always,
// so IEEE bits are u32-order-monotone; pk = (bits & KMASK) | tcv is ONE
// v_and_or_b32 (vs cvt+lshl_or).
// __launch_bounds__(512, 6): the r5 regression was this kernel spilling at
// the 64-VGPR cap implied by (512,8) — float-key codegen needs a few more
// temps than integer keys (~63 VGPR).  Cap ~85 removes the spill; measured
// occupancy was 57% anyway, and issue-bound code needs only ~2 waves/SIMD.
__global__ __launch_bounds__(512, 6) void vq_argmin(const float* __restrict__ z,
                                                    const ushort_t* __restrict__ ehi,
                                                    unsigned* __restrict__ candk) {
  __shared__ __align__(16) unsigned char smem[36864]; // dbuf 2x16KB;
  ushort_t* s_buf = (ushort_t*)smem;                  // merge: 256x36 words (36.9KB)

  const int tid = threadIdx.x;
  const int wave = tid >> 6, lane = tid & 63;
  const int q = lane >> 4, c = lane & 15;
  const int row0 = blockIdx.y * BROWS + wave * WROWS;
  const int nbase = blockIdx.x * NPB;

  // A fragments: two row-groups of 16, bf16(RNE) of -2^22*z in-register.
  bf16x8 zA[2][2];
  #pragma unroll
  for (int g = 0; g < 2; ++g) {
    const float* zr = z + (size_t)(row0 + g * 16 + c) * D_DIM;
    float4 a0 = *(const float4*)(zr + q * 8);
    float4 a1 = *(const float4*)(zr + q * 8 + 4);
    float4 a2 = *(const float4*)(zr + 32 + q * 8);
    float4 a3 = *(const float4*)(zr + 32 + q * 8 + 4);
    zA[g][0][0] = (short)bf16_rne(a0.x * ASCALE); zA[g][0][1] = (short)bf16_rne(a0.y * ASCALE);
    zA[g][0][2] = (short)bf16_rne(a0.z * ASCALE); zA[g][0][3] = (short)bf16_rne(a0.w * ASCALE);
    zA[g][0][4] = (short)bf16_rne(a1.x * ASCALE); zA[g][0][5] = (short)bf16_rne(a1.y * ASCALE);
    zA[g][0][6] = (short)bf16_rne(a1.z * ASCALE); zA[g][0][7] = (short)bf16_rne(a1.w * ASCALE);
    zA[g][1][0] = (short)bf16_rne(a2.x * ASCALE); zA[g][1][1] = (short)bf16_rne(a2.y * ASCALE);
    zA[g][1][2] = (short)bf16_rne(a2.z * ASCALE); zA[g][1][3] = (short)bf16_rne(a2.w * ASCALE);
    zA[g][1][4] = (short)bf16_rne(a3.x * ASCALE); zA[g][1][5] = (short)bf16_rne(a3.y * ASCALE);
    zA[g][1][6] = (short)bf16_rne(a3.z * ASCALE); zA[g][1][7] = (short)bf16_rne(a3.w * ASCALE);
  }

  const f32x4 cvec = {KBIAS_F, KBIAS_F, KBIAS_F, KBIAS_F}; // hoisted constant C

  // per-(rowgroup g, acc row r) top-2 packed-key tracking, K0 <= K1 invariant
  unsigned K0[2][4], K1[2][4];
  #pragma unroll
  for (int g = 0; g < 2; ++g)
    #pragma unroll
    for (int r = 0; r < 4; ++r) { K0[g][r] = 0xFFFFFFFFu; K1[g][r] = 0xFFFFFFFFu; }

  // prologue: async-stage chunk 0 into buf0 (2 DMA instructions per wave)
  {
    const ushort_t* g = ehi + (size_t)nbase * 64 + wave * 1024 + lane * 8;
    ushort_t* l = s_buf + wave * 1024 + lane * 8;
    load_lds16(g, l);
    load_lds16(g + 512, l + 512);
  }

  for (int cb = 0; cb < NCH; ++cb) {
    __syncthreads();   // vmcnt(0) waits loads(cb) — issued a compute-phase ago
    if (cb + 1 < NCH) {            // async-stage next chunk into the idle buffer
      int nnext = nbase + (cb + 1) * BN;
      const ushort_t* g = ehi + (size_t)nnext * 64 + wave * 1024 + lane * 8;
      ushort_t* l = s_buf + ((cb + 1) & 1) * 8192 + wave * 1024 + lane * 8;
      load_lds16(g, l);
      load_lds16(g + 512, l + 512);
    }
    const ushort_t* buf = s_buf + (cb & 1) * 8192;

    #pragma unroll
    for (int t = 0; t < BN / 16; ++t) {
      const bf16x8 bh0 = *(const bf16x8*)(buf + t * 1024 + lane * 8);
      const bf16x8 bh1 = *(const bf16x8*)(buf + t * 1024 + 512 + lane * 8);
      unsigned tcv = (((unsigned)(cb * 8 + t)) << 4) | (unsigned)c;  // n_local
      f32x4 acc0 = __builtin_amdgcn_mfma_f32_16x16x32_bf16(zA[0][0], bh0, cvec, 0, 0, 0);
      acc0 = __builtin_amdgcn_mfma_f32_16x16x32_bf16(zA[0][1], bh1, acc0, 0, 0, 0);
      f32x4 acc1 = __builtin_amdgcn_mfma_f32_16x16x32_bf16(zA[1][0], bh0, cvec, 0, 0, 0);
      acc1 = __builtin_amdgcn_mfma_f32_16x16x32_bf16(zA[1][1], bh1, acc1, 0, 0, 0);
      #pragma unroll
      for (int r = 0; r < 4; ++r) {
        unsigned pk = (__float_as_uint(acc0[r]) & KMASK) | tcv;  // 1-op and_or key
        K1[0][r] = umed3(pk, K0[0][r], K1[0][r]);
        K0[0][r] = min(pk, K0[0][r]);
      }
      #pragma unroll
      for (int r = 0; r < 4; ++r) {
        unsigned pk = (__float_as_uint(acc1[r]) & KMASK) | tcv;
        K1[1][r] = umed3(pk, K0[1][r], K1[1][r]);
        K0[1][r] = min(pk, K0[1][r]);
      }
    }
  }

  // merge 16 lanes' top-2 -> per-row top-4 keys (row stride 36 words: breaks
  // the all-lanes-same-bank-group pattern of stride 32)
  __syncthreads();
  unsigned* s_k = (unsigned*)smem;             // [256 rows][36 words]
  #pragma unroll
  for (int g = 0; g < 2; ++g)
    #pragma unroll
    for (int r = 0; r < 4; ++r) {
      int rowidx = wave * WROWS + g * 16 + q * 4 + r;  // C layout: row = q*4 + reg
      int base = rowidx * 36 + c * 2;
      s_k[base + 0] = K0[g][r]; s_k[base + 1] = K1[g][r];
    }
  __syncthreads();
  if (tid < BROWS) {
    unsigned M0 = 0xFFFFFFFFu, M1 = 0xFFFFFFFFu, M2 = 0xFFFFFFFFu, M3 = 0xFFFFFFFFu;
    const uint4* sv = (const uint4*)(s_k + tid * 36);
    #pragma unroll
    for (int v4 = 0; v4 < 8; ++v4) {
      uint4 kk = sv[v4];
      unsigned vals[4] = {kk.x, kk.y, kk.z, kk.w};
      #pragma unroll
      for (int u = 0; u < 4; ++u) {
        unsigned v = vals[u];
        M3 = umed3(v, M2, M3);
        M2 = umed3(v, M1, M2);
        M1 = umed3(v, M0, M1);
        M0 = min(v, M0);
      }
    }
    int grow = blockIdx.y * BROWS + tid;
    unsigned* cp = candk + ((size_t)grow * GCHUNKS + blockIdx.x) * 4;
    cp[0] = M0; cp[1] = M1; cp[2] = M2; cp[3] = M3;    // raw keys (fbits|n_local)
  }
}

// ------- kernel 3: key-pruned np-fp32-exact rescore, outputs ----------------
// grid = L/32 blocks, block 512 (8 waves); wave: 4 rows, 32 cand-groups x 2
// lanes.  qi = key>>12 = float bits >> 12 (20-bit, monotone in d).  minqi is
// reduced directly (no pack — 20-bit qi<<14 would overflow).  Window in steps
// derived from minqi's binade; see QDU comment at top.
__global__ __launch_bounds__(512, 6) void vq_refine(const float* __restrict__ z,
                                                    const float* __restrict__ e,
                                                    const float* __restrict__ esq32,
                                                    const float* __restrict__ zsq32,
                                                    const unsigned* __restrict__ candk,
                                                    float* __restrict__ out,
                                                    double* __restrict__ partials) {
  const int tid = threadIdx.x;
  const int wave = tid >> 6, lane = tid & 63;
  const int g = lane >> 1, s = lane & 1;      // 32 cand-groups x 2 lanes
  __shared__ double sp[8];
  double wl = 0.0;                             // per-lane loss partial
  for (int it = 0; it < 4; ++it) {
    int row = blockIdx.x * 32 + wave * 4 + it;
    float zf = z[(size_t)row * D_DIM + lane];
    float zsqv = zsq32[row];
    unsigned k = candk[(size_t)row * 32 + g];  // coalesced 128 B per row
    unsigned qi = k >> 12;                     // 20-bit float-hi-bits rank
    unsigned n  = ((unsigned)(g >> 2)) * (unsigned)NPB + (k & 4095u);
    unsigned m = qi;                           // reduce qi directly for minqi
    #pragma unroll
    for (int o = 1; o < 64; o <<= 1) m = min(m, (unsigned)__shfl_xor((int)m, o));
    // adaptive window: exp = m>>11 (sign=0); step = 2^(exp-138) acc-units
    unsigned shift = (m >> 11) - 138u;         // in {2,3,4} for reachable accs
    unsigned qd = (QDU >> shift) + 1u;         // covers >= QDU acc-units
    bool part = qi <= m + qd;
    unsigned long long key = ~0ull;
    if (part) {                                // both lanes of a pair agree
      const float4* ep = (const float4*)(e + (size_t)n * D_DIM + s * 32);
      const float4* zp = (const float4*)(z + (size_t)row * D_DIM + s * 32);
      double da = 0.0, db = 0.0, dc = 0.0, dd = 0.0;
      #pragma unroll
      for (int h = 0; h < 2; ++h) {
        float4 e0 = ep[h * 4 + 0], e1 = ep[h * 4 + 1];
        float4 e2 = ep[h * 4 + 2], e3 = ep[h * 4 + 3];
        float4 z0 = zp[h * 4 + 0], z1 = zp[h * 4 + 1];
        float4 z2 = zp[h * 4 + 2], z3 = zp[h * 4 + 3];
        da = fma((double)e0.x, (double)z0.x, da); da = fma((double)e0.y, (double)z0.y, da);
        da = fma((double)e0.z, (double)z0.z, da); da = fma((double)e0.w, (double)z0.w, da);
        db = fma((double)e1.x, (double)z1.x, db); db = fma((double)e1.y, (double)z1.y, db);
        db = fma((double)e1.z, (double)z1.z, db); db = fma((double)e1.w, (double)z1.w, db);
        dc = fma((double)e2.x, (double)z2.x, dc); dc = fma((double)e2.y, (double)z2.y, dc);
        dc = fma((double)e2.z, (double)z2.z, dc); dc = fma((double)e2.w, (double)z2.w, dc);
        dd = fma((double)e3.x, (double)z3.x, dd); dd = fma((double)e3.y, (double)z3.y, dd);
        dd = fma((double)e3.z, (double)z3.z, dd); dd = fma((double)e3.w, (double)z3.w, dd);
      }
      double dot = (da + db) + (dc + dd);
      dot += __shfl_xor(dot, 1);               // pair-mate has same `part`
      // emulate np fp32: d = fl32( fl32(zsq + esq) - fl32(2*dot) )
      float t2 = (float)(2.0 * dot);
      float T1 = zsqv + esq32[n];
      float d  = T1 - t2;                      // d ~ 64 > 0: bits are monotone
      key  = ((unsigned long long)__float_as_uint(d) << 14) | n;  // tie: lower n
    }
    #pragma unroll
    for (int o = 2; o <= 32; o <<= 1) {        // pair-mates equal; 5 steps
      unsigned long long ok = __shfl_xor(key, o);
      key = ok < key ? ok : key;
    }
    int win = (int)(key & 16383u);
    // outputs (element layout; whole wave)
    float be = e[(size_t)win * D_DIM + lane];
    out[(size_t)row * D_DIM + lane] = zf + (be - zf);   // fp32 op-order ST
    if (lane == 0) out[(size_t)L_TOK * D_DIM + 1 + row] = (float)win;
    double dd2 = (double)be - (double)zf;
    wl += dd2 * dd2;                           // per-lane loss contribution
  }
  #pragma unroll
  for (int o = 32; o; o >>= 1) wl += __shfl_xor(wl, o);
  if (lane == 0) sp[wave] = wl;
  __syncthreads();
  if (tid == 0) {
    double t = 0.0;
    #pragma unroll
    for (int w = 0; w < 8; ++w) t += sp[w];
    partials[blockIdx.x] = t;
  }
}

// ---------------- kernel 4: finalize loss (1024 partials) --------------------
__global__ __launch_bounds__(512) void vq_loss(const double* __restrict__ partials,
                                               float* __restrict__ out) {
  int tid = threadIdx.x;
  double v = partials[tid] + partials[tid + 512];
  #pragma unroll
  for (int o = 32; o; o >>= 1) v += __shfl_xor(v, o);
  __shared__ double sp[8];
  if ((tid & 63) == 0) sp[tid >> 6] = v;
  __syncthreads();
  if (tid == 0) {
    double tot = 0.0;
    #pragma unroll
    for (int w = 0; w < 8; ++w) tot += sp[w];
    // loss = beta*mean + mean = 1.25 * mean((z_q - z)^2)
    out[(size_t)L_TOK * D_DIM] = (float)(1.25 * tot / (double)((size_t)L_TOK * D_DIM));
  }
}

extern "C" void kernel_launch(void* const* d_in, const int* in_sizes, int n_in,
                              void* d_out, int out_size, void* d_ws, size_t ws_size,
                              hipStream_t stream) {
  const float* z = (const float*)d_in[0];       // (32768, 64) fp32
  const float* e = (const float*)d_in[1];       // (16384, 64) fp32
  float* out = (float*)d_out;                   // [z_q_st | loss | indices-as-f32]
  char* ws = (char*)d_ws;                       // needs ~6.3 MB

  ushort_t* ehi   = (ushort_t*)(ws + WS_EHI);
  float*    esq32 = (float*)(ws + WS_ESQ32);
  float*    zsq32 = (float*)(ws + WS_ZSQ32);
  unsigned* candk = (unsigned*)(ws + WS_CAND);
  double*   parts = (double*)(ws + WS_PART);

  vq_prep<<<EBLK + ZBLK, 256, 0, stream>>>(e, z, ehi, esq32, zsq32);
  vq_argmin<<<dim3(GCHUNKS, L_TOK / BROWS), 512, 0, stream>>>(z, ehi, candk);
  vq_refine<<<RBLOCKS, 512, 0, stream>>>(z, e, esq32, zsq32, candk, out, parts);
  vq_loss<<<1, 512, 0, stream>>>(parts, out);
}

// Round 8
// 183.510 us; speedup vs baseline: 1.2000x; 1.0095x over previous
//
#include <hip/hip_runtime.h>
#include <cstdint>
#include <cstddef>

// Problem constants (VectorQuantizer: L=32768, D=64, N_E=16384, beta=0.25)
#define L_TOK 32768
#define D_DIM 64
#define NE    16384
#define GCHUNKS 8              // N split across grid (8 -> 8192 waves total)
#define NPB   (NE / GCHUNKS)   // 2048 n per block
#define BN    128              // n per LDS stage chunk (double-buffered)
#define NCH   (NPB / BN)       // 16 chunks per block
#define WROWS 32               // rows per wave (2 MFMA row-groups)
#define BROWS 256              // rows per block (8 waves x 32)
#define RBLOCKS  (L_TOK / 32)  // 1024 refine blocks
#define EBLK  (NE / 4)         // prep blocks doing e rows
#define ZBLK  (L_TOK / 4)      // prep blocks doing z rows

#define ASCALE  -4194304.0f    // -2^22: A-fragment pre-scale (exact pow2)
#define KBIAS_F  32768.0f      // 2^15 bias as constant MFMA C operand.
                               // esq*2^21 <= 0.5 acc-units: dropped from sieve;
                               // exact esq32 still used in rescore.
#define KMASK    0xFFFFF000u   // float-bit key: top 20 bits of acc, idx in low 12
#define QDU      168u          // prune window in ACC-UNITS (160 proven + 8 esq-drop)
// Window in key-steps is computed adaptively in vq_refine from minqi's binade:
// masked-key granularity = 2^12 ulps = 2^(exp-138) acc-units.  acc in ~(10k,
// 57k) by C-S -> exp in {140,141,142} -> step {4,8,16} units -> steps
// qd = (QDU >> (exp-138)) + 1 = {43,22,11} covers {172,176,176} >= QDU units.
// Proven r5/r7 (absmax 0 both).

typedef unsigned short ushort_t;
typedef __attribute__((ext_vector_type(8))) short bf16x8;
typedef __attribute__((ext_vector_type(4))) float f32x4;

// ---- ws layout (bytes) ----
#define WS_EHI   0u                                  // 2 MB   e bf16(RNE) permuted
#define WS_ESQ32 (2u<<20)                            // 64 KB  esq np-exact fp32
#define WS_ESQS  ((2u<<20) + (64u<<10))              // 64 KB  (reserved, unused)
#define WS_ZSQ32 ((2u<<20) + (128u<<10))             // 128 KB zsq np-exact fp32
#define WS_CAND  ((2u<<20) + (256u<<10))             // 4 MB   candkeys[L][8][4] u32
#define WS_PART  ((6u<<20) + (256u<<10))             // 8 KB   loss partials (1024 dbl)

__device__ __forceinline__ ushort_t bf16_rne(float v) {
  unsigned u = __float_as_uint(v);
  return (ushort_t)((u + 0x7fffu + ((u >> 16) & 1u)) >> 16);
}

// v_med3_u32: median(a,b,c). With b<=c this equals min(max(a,b),c) — the
// top-k insertion step; asked for directly since the compiler can't prove
// the K-ordering invariant.  (Proven safe: present in every passing run.)
__device__ __forceinline__ unsigned umed3(unsigned a, unsigned b, unsigned c) {
  unsigned d;
  asm("v_med3_u32 %0, %1, %2, %3" : "=v"(d) : "v"(a), "v"(b), "v"(c));
  return d;
}

// async global->LDS DMA, 16 B/lane (no VGPR round-trip; counts in vmcnt)
__device__ __forceinline__ void load_lds16(const ushort_t* g, ushort_t* l) {
  __builtin_amdgcn_global_load_lds(
      (const __attribute__((address_space(1))) void*)g,
      (__attribute__((address_space(3))) void*)l, 16, 0, 0);
}

// numpy pairwise_sum emulation for n=64 contiguous fp32 (scalar 8-acc path).
__device__ __forceinline__ float np_sum64(float a) {
  int j = threadIdx.x & 7;
  float r = __shfl(a, j);
  #pragma unroll
  for (int m = 1; m < 8; ++m) r += __shfl(a, j + 8 * m);
  float s0 = __shfl(r, 0), s1 = __shfl(r, 1), s2 = __shfl(r, 2), s3 = __shfl(r, 3);
  float s4 = __shfl(r, 4), s5 = __shfl(r, 5), s6 = __shfl(r, 6), s7 = __shfl(r, 7);
  return ((s0 + s1) + (s2 + s3)) + ((s4 + s5) + (s6 + s7));
}

// Fragment-permuted index (in ushorts) for element (n, k) — LDS staging order
// equals MFMA B-fragment consumption order (conflict-free ds_read_b128).
__device__ __forceinline__ int perm_off(int n, int k) {
  int tile = n >> 4, c = n & 15, s = k >> 5, q = (k >> 3) & 3, j = k & 7;
  return tile * 1024 + s * 512 + (q * 16 + c) * 8 + j;
}

// ---------------- kernel 1: combined prep (e rows, then z rows) --------------
__global__ __launch_bounds__(256) void vq_prep(const float* __restrict__ e,
                                               const float* __restrict__ z,
                                               ushort_t* __restrict__ ehi,
                                               float* __restrict__ esq32,
                                               float* __restrict__ zsq32) {
  int wave = threadIdx.x >> 6, lane = threadIdx.x & 63;
  if (blockIdx.x < EBLK) {
    int row = blockIdx.x * 4 + wave;          // one wave per embedding row
    float v = e[(size_t)row * D_DIM + lane];
    ehi[perm_off(row, lane)] = bf16_rne(v);
    float esq = np_sum64(v * v);              // numpy-bit-exact sum(e*e, axis=1)
    if (lane == 0) esq32[row] = esq;          // exact rescore only (sieve drops esq)
  } else {
    int row = (blockIdx.x - EBLK) * 4 + wave; // one wave per z row
    float v = z[(size_t)row * D_DIM + lane];
    float s = np_sum64(v * v);                // numpy-bit-exact sum(z*z, axis=1)
    if (lane == 0) zsq32[row] = s;
  }
}

// ---------------- kernel 2: fused distance + per-row top-k sieve -------------
// grid = dim3(GCHUNKS, L/BROWS) = 1024 blocks, block = 512 (8 waves x 32 rows)
// Issue-saturated (VALU 67% + MFMA 28%); sieve insert = 3 ops (and_or key +
// med3 + min) — structural floor for exact top-2.  UNCHANGED from r7 (103us,
// FETCH 33.9MB WRITE 8.2MB — clean, no spill at (512,6)).
__global__ __launch_bounds__(512, 6) void vq_argmin(const float* __restrict__ z,
                                                    const ushort_t* __restrict__ ehi,
                                                    unsigned* __restrict__ candk) {
  __shared__ __align__(16) unsigned char smem[36864]; // dbuf 2x16KB;
  ushort_t* s_buf = (ushort_t*)smem;                  // merge: 256x36 words (36.9KB)

  const int tid = threadIdx.x;
  const int wave = tid >> 6, lane = tid & 63;
  const int q = lane >> 4, c = lane & 15;
  const int row0 = blockIdx.y * BROWS + wave * WROWS;
  const int nbase = blockIdx.x * NPB;

  // A fragments: two row-groups of 16, bf16(RNE) of -2^22*z in-register.
  bf16x8 zA[2][2];
  #pragma unroll
  for (int g = 0; g < 2; ++g) {
    const float* zr = z + (size_t)(row0 + g * 16 + c) * D_DIM;
    float4 a0 = *(const float4*)(zr + q * 8);
    float4 a1 = *(const float4*)(zr + q * 8 + 4);
    float4 a2 = *(const float4*)(zr + 32 + q * 8);
    float4 a3 = *(const float4*)(zr + 32 + q * 8 + 4);
    zA[g][0][0] = (short)bf16_rne(a0.x * ASCALE); zA[g][0][1] = (short)bf16_rne(a0.y * ASCALE);
    zA[g][0][2] = (short)bf16_rne(a0.z * ASCALE); zA[g][0][3] = (short)bf16_rne(a0.w * ASCALE);
    zA[g][0][4] = (short)bf16_rne(a1.x * ASCALE); zA[g][0][5] = (short)bf16_rne(a1.y * ASCALE);
    zA[g][0][6] = (short)bf16_rne(a1.z * ASCALE); zA[g][0][7] = (short)bf16_rne(a1.w * ASCALE);
    zA[g][1][0] = (short)bf16_rne(a2.x * ASCALE); zA[g][1][1] = (short)bf16_rne(a2.y * ASCALE);
    zA[g][1][2] = (short)bf16_rne(a2.z * ASCALE); zA[g][1][3] = (short)bf16_rne(a2.w * ASCALE);
    zA[g][1][4] = (short)bf16_rne(a3.x * ASCALE); zA[g][1][5] = (short)bf16_rne(a3.y * ASCALE);
    zA[g][1][6] = (short)bf16_rne(a3.z * ASCALE); zA[g][1][7] = (short)bf16_rne(a3.w * ASCALE);
  }

  const f32x4 cvec = {KBIAS_F, KBIAS_F, KBIAS_F, KBIAS_F}; // hoisted constant C

  // per-(rowgroup g, acc row r) top-2 packed-key tracking, K0 <= K1 invariant
  unsigned K0[2][4], K1[2][4];
  #pragma unroll
  for (int g = 0; g < 2; ++g)
    #pragma unroll
    for (int r = 0; r < 4; ++r) { K0[g][r] = 0xFFFFFFFFu; K1[g][r] = 0xFFFFFFFFu; }

  // prologue: async-stage chunk 0 into buf0 (2 DMA instructions per wave)
  {
    const ushort_t* g = ehi + (size_t)nbase * 64 + wave * 1024 + lane * 8;
    ushort_t* l = s_buf + wave * 1024 + lane * 8;
    load_lds16(g, l);
    load_lds16(g + 512, l + 512);
  }

  for (int cb = 0; cb < NCH; ++cb) {
    __syncthreads();   // vmcnt(0) waits loads(cb) — issued a compute-phase ago
    if (cb + 1 < NCH) {            // async-stage next chunk into the idle buffer
      int nnext = nbase + (cb + 1) * BN;
      const ushort_t* g = ehi + (size_t)nnext * 64 + wave * 1024 + lane * 8;
      ushort_t* l = s_buf + ((cb + 1) & 1) * 8192 + wave * 1024 + lane * 8;
      load_lds16(g, l);
      load_lds16(g + 512, l + 512);
    }
    const ushort_t* buf = s_buf + (cb & 1) * 8192;

    #pragma unroll
    for (int t = 0; t < BN / 16; ++t) {
      const bf16x8 bh0 = *(const bf16x8*)(buf + t * 1024 + lane * 8);
      const bf16x8 bh1 = *(const bf16x8*)(buf + t * 1024 + 512 + lane * 8);
      unsigned tcv = (((unsigned)(cb * 8 + t)) << 4) | (unsigned)c;  // n_local
      f32x4 acc0 = __builtin_amdgcn_mfma_f32_16x16x32_bf16(zA[0][0], bh0, cvec, 0, 0, 0);
      acc0 = __builtin_amdgcn_mfma_f32_16x16x32_bf16(zA[0][1], bh1, acc0, 0, 0, 0);
      f32x4 acc1 = __builtin_amdgcn_mfma_f32_16x16x32_bf16(zA[1][0], bh0, cvec, 0, 0, 0);
      acc1 = __builtin_amdgcn_mfma_f32_16x16x32_bf16(zA[1][1], bh1, acc1, 0, 0, 0);
      #pragma unroll
      for (int r = 0; r < 4; ++r) {
        unsigned pk = (__float_as_uint(acc0[r]) & KMASK) | tcv;  // 1-op and_or key
        K1[0][r] = umed3(pk, K0[0][r], K1[0][r]);
        K0[0][r] = min(pk, K0[0][r]);
      }
      #pragma unroll
      for (int r = 0; r < 4; ++r) {
        unsigned pk = (__float_as_uint(acc1[r]) & KMASK) | tcv;
        K1[1][r] = umed3(pk, K0[1][r], K1[1][r]);
        K0[1][r] = min(pk, K0[1][r]);
      }
    }
  }

  // merge 16 lanes' top-2 -> per-row top-4 keys (row stride 36 words: breaks
  // the all-lanes-same-bank-group pattern of stride 32)
  __syncthreads();
  unsigned* s_k = (unsigned*)smem;             // [256 rows][36 words]
  #pragma unroll
  for (int g = 0; g < 2; ++g)
    #pragma unroll
    for (int r = 0; r < 4; ++r) {
      int rowidx = wave * WROWS + g * 16 + q * 4 + r;  // C layout: row = q*4 + reg
      int base = rowidx * 36 + c * 2;
      s_k[base + 0] = K0[g][r]; s_k[base + 1] = K1[g][r];
    }
  __syncthreads();
  if (tid < BROWS) {
    unsigned M0 = 0xFFFFFFFFu, M1 = 0xFFFFFFFFu, M2 = 0xFFFFFFFFu, M3 = 0xFFFFFFFFu;
    const uint4* sv = (const uint4*)(s_k + tid * 36);
    #pragma unroll
    for (int v4 = 0; v4 < 8; ++v4) {
      uint4 kk = sv[v4];
      unsigned vals[4] = {kk.x, kk.y, kk.z, kk.w};
      #pragma unroll
      for (int u = 0; u < 4; ++u) {
        unsigned v = vals[u];
        M3 = umed3(v, M2, M3);
        M2 = umed3(v, M1, M2);
        M1 = umed3(v, M0, M1);
        M0 = min(v, M0);
      }
    }
    int grow = blockIdx.y * BROWS + tid;
    unsigned* cp = candk + ((size_t)grow * GCHUNKS + blockIdx.x) * 4;
    cp[0] = M0; cp[1] = M1; cp[2] = M2; cp[3] = M3;    // raw keys (fbits|n_local)
  }
}

// ------- kernel 3: key-pruned np-fp32-exact rescore, outputs ----------------
// grid = L/32 blocks, block 512 (8 waves); wave: 4 rows, 32 cand-groups x 2
// lanes.  v2: LATENCY-bound kernel (r6: +1 shuffle chain per row cost +7us,
// 6x a throughput model) -> software-pipeline the 4 rows: all loads issued
// first, then the two shuffle-reduce chains run 4-way INTERLEAVED (hides the
// ~8-cyc shuffle latency), gathers batched before stores.  Per-row fp op
// order is bit-identical to r7 (interleave crosses rows only).
// __launch_bounds__(512,4): 4-way live state (~76 VGPR peak incl. the fp64
// dot block) needs the 128-reg cap; (512,6)'s 85 could spill (r5 lesson).
__global__ __launch_bounds__(512, 4) void vq_refine(const float* __restrict__ z,
                                                    const float* __restrict__ e,
                                                    const float* __restrict__ esq32,
                                                    const float* __restrict__ zsq32,
                                                    const unsigned* __restrict__ candk,
                                                    float* __restrict__ out,
                                                    double* __restrict__ partials) {
  const int tid = threadIdx.x;
  const int wave = tid >> 6, lane = tid & 63;
  const int g = lane >> 1, s = lane & 1;      // 32 cand-groups x 2 lanes
  __shared__ double sp[8];
  const int rbase = blockIdx.x * 32 + wave * 4;

  // phase 1: issue all independent loads (4 rows x {zf, zsq, candk})
  float zf[4], zsqv[4];
  unsigned k[4];
  #pragma unroll
  for (int it = 0; it < 4; ++it) {
    int row = rbase + it;
    zf[it]   = z[(size_t)row * D_DIM + lane];
    zsqv[it] = zsq32[row];                    // wave-uniform -> s_load
    k[it]    = candk[(size_t)row * 32 + g];   // coalesced 128 B per row
  }

  // phase 2: four 6-step min-reduces, interleaved (4-way ILP on shuffle lat)
  unsigned qi[4], nn[4], m[4];
  #pragma unroll
  for (int it = 0; it < 4; ++it) {
    qi[it] = k[it] >> 12;                     // 20-bit float-hi-bits rank
    nn[it] = ((unsigned)(g >> 2)) * (unsigned)NPB + (k[it] & 4095u);
    m[it]  = qi[it];
  }
  #pragma unroll
  for (int o = 1; o < 64; o <<= 1) {
    #pragma unroll
    for (int it = 0; it < 4; ++it)
      m[it] = min(m[it], (unsigned)__shfl_xor((int)m[it], o));
  }

  // phase 3: adaptive window + pruned fp64 dots (rare path, per it)
  unsigned long long key[4];
  #pragma unroll
  for (int it = 0; it < 4; ++it) {
    unsigned shift = (m[it] >> 11) - 138u;    // in {2,3,4} for reachable accs
    unsigned qd = (QDU >> shift) + 1u;        // covers >= QDU acc-units
    bool part = qi[it] <= m[it] + qd;
    key[it] = ~0ull;
    if (part) {                               // both lanes of a pair agree
      int row = rbase + it;
      const float4* ep = (const float4*)(e + (size_t)nn[it] * D_DIM + s * 32);
      const float4* zp = (const float4*)(z + (size_t)row * D_DIM + s * 32);
      double da = 0.0, db = 0.0, dc = 0.0, dd = 0.0;
      #pragma unroll
      for (int h = 0; h < 2; ++h) {
        float4 e0 = ep[h * 4 + 0], e1 = ep[h * 4 + 1];
        float4 e2 = ep[h * 4 + 2], e3 = ep[h * 4 + 3];
        float4 z0 = zp[h * 4 + 0], z1 = zp[h * 4 + 1];
        float4 z2 = zp[h * 4 + 2], z3 = zp[h * 4 + 3];
        da = fma((double)e0.x, (double)z0.x, da); da = fma((double)e0.y, (double)z0.y, da);
        da = fma((double)e0.z, (double)z0.z, da); da = fma((double)e0.w, (double)z0.w, da);
        db = fma((double)e1.x, (double)z1.x, db); db = fma((double)e1.y, (double)z1.y, db);
        db = fma((double)e1.z, (double)z1.z, db); db = fma((double)e1.w, (double)z1.w, db);
        dc = fma((double)e2.x, (double)z2.x, dc); dc = fma((double)e2.y, (double)z2.y, dc);
        dc = fma((double)e2.z, (double)z2.z, dc); dc = fma((double)e2.w, (double)z2.w, dc);
        dd = fma((double)e3.x, (double)z3.x, dd); dd = fma((double)e3.y, (double)z3.y, dd);
        dd = fma((double)e3.z, (double)z3.z, dd); dd = fma((double)e3.w, (double)z3.w, dd);
      }
      double dot = (da + db) + (dc + dd);
      dot += __shfl_xor(dot, 1);              // pair-mate has same `part`
      // emulate np fp32: d = fl32( fl32(zsq + esq) - fl32(2*dot) )
      float t2 = (float)(2.0 * dot);
      float T1 = zsqv[it] + esq32[nn[it]];
      float d  = T1 - t2;                     // d ~ 64 > 0: bits are monotone
      key[it] = ((unsigned long long)__float_as_uint(d) << 14) | nn[it]; // tie: lower n
    }
  }

  // phase 4: four 5-step 64-bit key reduces, interleaved
  #pragma unroll
  for (int o = 2; o <= 32; o <<= 1) {         // pair-mates equal; 5 steps
    #pragma unroll
    for (int it = 0; it < 4; ++it) {
      unsigned long long ok = __shfl_xor(key[it], o);
      key[it] = ok < key[it] ? ok : key[it];
    }
  }

  // phase 5: batched gathers, then stores + loss (it-order preserved)
  int win[4];
  float be[4];
  #pragma unroll
  for (int it = 0; it < 4; ++it) {
    win[it] = (int)(key[it] & 16383u);        // wave-uniform after reduce
    be[it]  = e[(size_t)win[it] * D_DIM + lane];  // coalesced 256 B row
  }
  double wl = 0.0;                            // per-lane loss partial
  #pragma unroll
  for (int it = 0; it < 4; ++it) {
    int row = rbase + it;
    out[(size_t)row * D_DIM + lane] = zf[it] + (be[it] - zf[it]); // fp32 op-order ST
    if (lane == 0) out[(size_t)L_TOK * D_DIM + 1 + row] = (float)win[it];
    double dd2 = (double)be[it] - (double)zf[it];
    wl += dd2 * dd2;                          // same it-order accumulation as r7
  }
  #pragma unroll
  for (int o = 32; o; o >>= 1) wl += __shfl_xor(wl, o);
  if (lane == 0) sp[wave] = wl;
  __syncthreads();
  if (tid == 0) {
    double t = 0.0;
    #pragma unroll
    for (int w = 0; w < 8; ++w) t += sp[w];
    partials[blockIdx.x] = t;
  }
}

// ---------------- kernel 4: finalize loss (1024 partials) --------------------
__global__ __launch_bounds__(512) void vq_loss(const double* __restrict__ partials,
                                               float* __restrict__ out) {
  int tid = threadIdx.x;
  double v = partials[tid] + partials[tid + 512];
  #pragma unroll
  for (int o = 32; o; o >>= 1) v += __shfl_xor(v, o);
  __shared__ double sp[8];
  if ((tid & 63) == 0) sp[tid >> 6] = v;
  __syncthreads();
  if (tid == 0) {
    double tot = 0.0;
    #pragma unroll
    for (int w = 0; w < 8; ++w) tot += sp[w];
    // loss = beta*mean + mean = 1.25 * mean((z_q - z)^2)
    out[(size_t)L_TOK * D_DIM] = (float)(1.25 * tot / (double)((size_t)L_TOK * D_DIM));
  }
}

extern "C" void kernel_launch(void* const* d_in, const int* in_sizes, int n_in,
                              void* d_out, int out_size, void* d_ws, size_t ws_size,
                              hipStream_t stream) {
  const float* z = (const float*)d_in[0];       // (32768, 64) fp32
  const float* e = (const float*)d_in[1];       // (16384, 64) fp32
  float* out = (float*)d_out;                   // [z_q_st | loss | indices-as-f32]
  char* ws = (char*)d_ws;                       // needs ~6.3 MB

  ushort_t* ehi   = (ushort_t*)(ws + WS_EHI);
  float*    esq32 = (float*)(ws + WS_ESQ32);
  float*    zsq32 = (float*)(ws + WS_ZSQ32);
  unsigned* candk = (unsigned*)(ws + WS_CAND);
  double*   parts = (double*)(ws + WS_PART);

  vq_prep<<<EBLK + ZBLK, 256, 0, stream>>>(e, z, ehi, esq32, zsq32);
  vq_argmin<<<dim3(GCHUNKS, L_TOK / BROWS), 512, 0, stream>>>(z, ehi, candk);
  vq_refine<<<RBLOCKS, 512, 0, stream>>>(z, e, esq32, zsq32, candk, out, parts);
  vq_loss<<<1, 512, 0, stream>>>(parts, out);
}